// Round 4
// baseline (193.547 us; speedup 1.0000x reference)
//
#include <hip/hip_runtime.h>
#include <hip/hip_bf16.h>
#include <cstdint>
#include <cstddef>

// ---------- types ----------
typedef __attribute__((ext_vector_type(8))) _Float16 half8;
typedef __attribute__((ext_vector_type(4))) float floatx4;

#define MFMA16(a, b, c) __builtin_amdgcn_mfma_f32_16x16x32_f16((a), (b), (c), 0, 0, 0)

// direct global->LDS DMA, 16B per lane, dest = uniform base + lane*16
#define GLOAD_LDS16(g, l)                                                     \
    __builtin_amdgcn_global_load_lds(                                         \
        (const __attribute__((address_space(1))) void*)(g),                   \
        (__attribute__((address_space(3))) void*)(l), 16, 0, 0)

// Problem constants: A=64, T=512, D=256, H=4, HD=64
#define NFEAT 8388608   // 64*512*256

// ---------- staging helpers (128 rows x 64 k-cols -> packed LDS [128][64],
//            XOR chunk swizzle so ds_read_b128 frag reads are conflict-free) ----

// fp16 source via global_load_lds DMA (src row stride 256 halfs)
__device__ __forceinline__ void stage_dma(
    const _Float16* __restrict__ src, _Float16* __restrict__ lds,
    int wid, int lane)
{
#pragma unroll
    for (int i = 0; i < 4; ++i) {
        int grp = wid * 4 + i;             // 16 groups of 8 rows
        int row = grp * 8 + (lane >> 3);
        int sc  = (lane & 7) ^ (row & 7);  // source chunk for this dest slot
        GLOAD_LDS16(src + (size_t)row * 256 + sc * 8, lds + grp * 512);
    }
}

// fp32 source, converted in-register (src row stride 256 floats)
__device__ __forceinline__ void stage_f32(
    const float* __restrict__ src, _Float16* __restrict__ lds, int tid)
{
#pragma unroll
    for (int i = 0; i < 4; ++i) {
        int g   = tid + 256 * i;           // 1024 groups of 8 halfs
        int row = g >> 3, chd = g & 7;
        int chs = chd ^ (row & 7);
        const float* s = src + (size_t)row * 256 + chs * 8;
        float4 v0 = *(const float4*)s;
        float4 v1 = *(const float4*)(s + 4);
        half8 h = { (_Float16)v0.x, (_Float16)v0.y, (_Float16)v0.z, (_Float16)v0.w,
                    (_Float16)v1.x, (_Float16)v1.y, (_Float16)v1.z, (_Float16)v1.w };
        *(half8*)(&lds[row * 64 + chd * 8]) = h;
    }
}

// ---------- NT GEMM: C[128x128] = X[128x256] * W[256x256 rows bn*128..]^T + bias
// BM=BN=128, BK=64, 4 waves (2x2), wave tile 64x64. W always fp32 (inline cvt).
template <bool XF32, bool OUT_HALF>
__device__ __forceinline__ void gemm128x128(
    const void* __restrict__ Xv, const float* __restrict__ Wf,
    const float* __restrict__ bias, void* __restrict__ Cptr, int bm, int bn)
{
    __shared__ _Float16 As[128 * 64];
    __shared__ _Float16 Bs[128 * 64];

    const int tid  = threadIdx.x;
    const int lane = tid & 63, wid = tid >> 6;
    const int quad = lane >> 4, l16 = lane & 15;
    const int wm = wid & 1, wn = wid >> 1;

    floatx4 acc[4][4] = {};
    const float* Wg = Wf + (size_t)bn * 128 * 256;

    for (int k0 = 0; k0 < 256; k0 += 64) {
        if (XF32)
            stage_f32(((const float*)Xv) + (size_t)bm * 128 * 256 + k0, As, tid);
        else
            stage_dma(((const _Float16*)Xv) + (size_t)bm * 128 * 256 + k0, As, wid, lane);
        stage_f32(Wg + k0, Bs, tid);
        __syncthreads();
#pragma unroll
        for (int kh = 0; kh < 2; ++kh) {
            half8 af[4], bf[4];
#pragma unroll
            for (int mi = 0; mi < 4; ++mi) {
                int row = wm * 64 + mi * 16 + l16;
                int ch  = (kh * 4 + quad) ^ (l16 & 7);
                af[mi] = *(const half8*)(&As[row * 64 + ch * 8]);
            }
#pragma unroll
            for (int ni = 0; ni < 4; ++ni) {
                int row = wn * 64 + ni * 16 + l16;
                int ch  = (kh * 4 + quad) ^ (l16 & 7);
                bf[ni] = *(const half8*)(&Bs[row * 64 + ch * 8]);
            }
#pragma unroll
            for (int mi = 0; mi < 4; ++mi)
#pragma unroll
                for (int ni = 0; ni < 4; ++ni)
                    acc[mi][ni] = MFMA16(af[mi], bf[ni], acc[mi][ni]);
        }
        __syncthreads();
    }

    // epilogue: C/D layout col = lane&15, row = quad*4 + r
#pragma unroll
    for (int ni = 0; ni < 4; ++ni) {
        int col = bn * 128 + wn * 64 + ni * 16 + l16;
        float bv = bias[col];
#pragma unroll
        for (int mi = 0; mi < 4; ++mi) {
#pragma unroll
            for (int r = 0; r < 4; ++r) {
                int row = bm * 128 + wm * 64 + mi * 16 + quad * 4 + r;
                float v = acc[mi][ni][r] + bv;
                if (OUT_HALF)
                    ((_Float16*)Cptr)[(size_t)row * 256 + col] = (_Float16)v;
                else
                    ((float*)Cptr)[(size_t)row * 256 + col] = v;
            }
        }
    }
}

// grid: x = z*2+bn (0..5, fastest -> 6 blocks sharing an X tile adjacent), y = bm
__global__ __launch_bounds__(256) void qkv_gemm(
    const float* __restrict__ feat,
    const float* __restrict__ Wq, const float* __restrict__ Wk,
    const float* __restrict__ Wv,
    const float* __restrict__ bq, const float* __restrict__ bk,
    const float* __restrict__ bv,
    _Float16* __restrict__ Qb, _Float16* __restrict__ Kb, _Float16* __restrict__ Vb)
{
    int z = blockIdx.x >> 1, bn = blockIdx.x & 1;
    const float* W    = (z == 0) ? Wq : (z == 1) ? Wk : Wv;
    const float* bias = (z == 0) ? bq : (z == 1) ? bk : bv;
    _Float16* out     = (z == 0) ? Qb : (z == 1) ? Kb : Vb;
    gemm128x128<true, true>(feat, W, bias, out, blockIdx.y, bn);
}

__global__ __launch_bounds__(256) void out_gemm(
    const _Float16* __restrict__ attnH, const float* __restrict__ Wo,
    const float* __restrict__ bo, float* __restrict__ out)
{
    gemm128x128<false, false>(attnH, Wo, bo, out, blockIdx.y, blockIdx.x);
}

// ---------- banded sparse attention ----------
// grid: x = qtile (0..7, 64 q rows each), y = head (0..3), z = animal (0..63)
// key band: s in [q0-64, q0+127] (width 192) covers |t-s|<=64 for all rows
__global__ __launch_bounds__(256) void attn_kernel(
    const _Float16* __restrict__ Qb, const _Float16* __restrict__ Kb,
    const _Float16* __restrict__ Vb, const float* __restrict__ positions,
    const int* __restrict__ mdp, const int* __restrict__ twp,
    _Float16* __restrict__ attnb)
{
    const int qt = blockIdx.x, h = blockIdx.y, a = blockIdx.z;
    const int q0 = qt * 64;
    const int s_base = q0 - 64;
    const int tid = threadIdx.x, lane = tid & 63, wid = tid >> 6;
    const int quad = lane >> 4, l16 = lane & 15;

    // LDS 49.7 KB: packed K [192][64] (XOR-swizzled, reused as packed P),
    // Vt [64][196]
    __shared__ _Float16 KPs[192 * 64];
    __shared__ _Float16 Vt[64 * 196];

    const size_t abase = (size_t)a * 512;
    const int md = *mdp, tw = *twp;
    const float md2 = (float)(md * md);

    // ---- hoisted per-wave Q fragment + q-position loads (overlap staging) ----
    const size_t qrow = abase + q0 + wid * 16 + l16;
    half8 aq0 = *(const half8*)(Qb + qrow * 256 + h * 64 + quad * 8);
    half8 aq1 = *(const half8*)(Qb + qrow * 256 + h * 64 + 32 + quad * 8);
    float qpx[4], qpy[4];
    int trow[4];
#pragma unroll
    for (int r = 0; r < 4; ++r) {
        int m = wid * 16 + quad * 4 + r;
        trow[r] = q0 + m;
        float2 qp = *(const float2*)(positions + (abase + q0 + m) * 2);
        qpx[r] = qp.x;
        qpy[r] = qp.y;
    }

    // ---- stage K band via DMA: packed [192][64], source-side XOR swizzle ----
#pragma unroll
    for (int i = 0; i < 6; ++i) {
        int grp = wid * 6 + i;             // 24 groups of 8 rows
        int si  = grp * 8 + (lane >> 3);
        int sc  = min(max(s_base + si, 0), 511);
        int ch  = (lane & 7) ^ (si & 7);
        GLOAD_LDS16(Kb + (abase + sc) * 256 + h * 64 + ch * 8, KPs + grp * 512);
    }
    // ---- stage V transposed with paired b32 writes ----
#pragma unroll
    for (int i = 0; i < 3; ++i) {
        int idx = tid + 256 * i;           // 768 pair-groups
        int si2 = (idx % 96) * 2;
        int d0  = (idx / 96) * 8;
        int sa  = min(max(s_base + si2, 0), 511);
        int sb  = min(max(s_base + si2 + 1, 0), 511);
        half8 v0 = *(const half8*)(Vb + (abase + sa) * 256 + h * 64 + d0);
        half8 v1 = *(const half8*)(Vb + (abase + sb) * 256 + h * 64 + d0);
#pragma unroll
        for (int j = 0; j < 8; ++j) {
            union { _Float16 hh[2]; uint32_t u; } p;
            p.hh[0] = v0[j]; p.hh[1] = v1[j];
            *(uint32_t*)(&Vt[(d0 + j) * 196 + si2]) = p.u;
        }
    }
    __syncthreads();

    // ---- S = Q K^T over 12 key tiles ----
    floatx4 S[12];
#pragma unroll
    for (int j = 0; j < 12; ++j) {
        int si = j * 16 + l16;
        half8 bk0 = *(const half8*)(&KPs[si * 64 + ((quad) ^ (si & 7)) * 8]);
        half8 bk1 = *(const half8*)(&KPs[si * 64 + ((4 + quad) ^ (si & 7)) * 8]);
        floatx4 acc = {};
        acc = MFMA16(aq0, bk0, acc);
        acc = MFMA16(aq1, bk1, acc);
        int sr = s_base + si;
        int sc = min(max(sr, 0), 511);
        float2 kp = *(const float2*)(positions + (abase + sc) * 2);
        bool svalid = (sr >= 0) && (sr < 512);
#pragma unroll
        for (int r = 0; r < 4; ++r) {
            float dx = qpx[r] - kp.x, dy = qpy[r] - kp.y;
            float d2 = dx * dx + dy * dy;
            int dt = trow[r] - sr; dt = dt < 0 ? -dt : dt;
            bool ok = svalid && (d2 <= md2) && (dt <= tw);
            S[j][r] = ok ? acc[r] * 0.125f : -1e30f;   // scale = 1/sqrt(64)
        }
    }

    // ---- softmax (exact; quad shuffles) ----
    float minv[4];
#pragma unroll
    for (int r = 0; r < 4; ++r) {
        float m = -1e30f;
#pragma unroll
        for (int j = 0; j < 12; ++j) m = fmaxf(m, S[j][r]);
        m = fmaxf(m, __shfl_xor(m, 1));
        m = fmaxf(m, __shfl_xor(m, 2));
        m = fmaxf(m, __shfl_xor(m, 4));
        m = fmaxf(m, __shfl_xor(m, 8));
        float l = 0.f;
#pragma unroll
        for (int j = 0; j < 12; ++j) {
            float p = __expf(S[j][r] - m);
            S[j][r] = p;
            l += p;
        }
        l += __shfl_xor(l, 1);
        l += __shfl_xor(l, 2);
        l += __shfl_xor(l, 4);
        l += __shfl_xor(l, 8);
        minv[r] = 1.0f / l;
    }

    __syncthreads();   // all waves done reading K before P overwrites it

    // ---- write P into packed-XOR A layout [wave][16][192] over the K region ----
    _Float16* Ps = KPs + wid * (16 * 192);
#pragma unroll
    for (int j = 0; j < 12; ++j)
#pragma unroll
        for (int r = 0; r < 4; ++r) {
            int row = quad * 4 + r;
            int col = j * 16 + l16;
            int ch  = (col >> 3) ^ (row & 7);
            Ps[row * 192 + ch * 8 + (col & 7)] = (_Float16)(S[j][r] * minv[r]);
        }

    // ---- O = P V : M=16, K=192 (6 steps), N=64 (4 tiles) ----
    half8 af[6];
#pragma unroll
    for (int k = 0; k < 6; ++k) {
        int ch = (k * 4 + quad) ^ (l16 & 7);
        af[k] = *(const half8*)(&Ps[l16 * 192 + ch * 8]);
    }
#pragma unroll
    for (int n = 0; n < 4; ++n) {
        floatx4 accO = {};
#pragma unroll
        for (int k = 0; k < 6; ++k) {
            half8 bv = *(const half8*)(&Vt[(n * 16 + l16) * 196 + k * 32 + quad * 8]);
            accO = MFMA16(af[k], bv, accO);
        }
#pragma unroll
        for (int r = 0; r < 4; ++r) {
            int row = q0 + wid * 16 + quad * 4 + r;
            attnb[(abase + row) * 256 + h * 64 + n * 16 + l16] = (_Float16)accO[r];
        }
    }
}

// ---------- launch ----------
extern "C" void kernel_launch(void* const* d_in, const int* in_sizes, int n_in,
                              void* d_out, int out_size, void* d_ws, size_t ws_size,
                              hipStream_t stream)
{
    const float* feat = (const float*)d_in[0];
    const float* pos  = (const float*)d_in[1];
    const float* Wq   = (const float*)d_in[2];
    const float* bq   = (const float*)d_in[3];
    const float* Wk   = (const float*)d_in[4];
    const float* bk   = (const float*)d_in[5];
    const float* Wv   = (const float*)d_in[6];
    const float* bv   = (const float*)d_in[7];
    const float* Wo   = (const float*)d_in[8];
    const float* bo   = (const float*)d_in[9];
    const int*   md   = (const int*)d_in[10];
    const int*   tw   = (const int*)d_in[11];
    float*       out  = (float*)d_out;

    _Float16* ws    = (_Float16*)d_ws;
    _Float16* Qb    = ws;
    _Float16* Kb    = Qb + NFEAT;
    _Float16* Vb    = Kb + NFEAT;
    _Float16* attnH = Vb + NFEAT;      // 4*16 MB = 64 MB of d_ws

    dim3 gqkv(6, 256);
    qkv_gemm<<<gqkv, 256, 0, stream>>>(feat, Wq, Wk, Wv, bq, bk, bv, Qb, Kb, Vb);

    dim3 gattn(8, 4, 64);
    attn_kernel<<<gattn, 256, 0, stream>>>(Qb, Kb, Vb, pos, md, tw, attnH);

    dim3 gout(2, 256);
    out_gemm<<<gout, 256, 0, stream>>>(attnH, Wo, bo, out);
}

// Round 5
// 167.671 us; speedup vs baseline: 1.1543x; 1.1543x over previous
//
#include <hip/hip_runtime.h>
#include <hip/hip_bf16.h>
#include <cstdint>
#include <cstddef>

// ---------- types ----------
typedef __attribute__((ext_vector_type(8))) _Float16 half8;
typedef __attribute__((ext_vector_type(4))) float floatx4;

#define MFMA16(a, b, c) __builtin_amdgcn_mfma_f32_16x16x32_f16((a), (b), (c), 0, 0, 0)

// direct global->LDS DMA, 16B per lane, dest = uniform base + lane*16
#define GLOAD_LDS16(g, l)                                                     \
    __builtin_amdgcn_global_load_lds(                                         \
        (const __attribute__((address_space(1))) void*)(g),                   \
        (__attribute__((address_space(3))) void*)(l), 16, 0, 0)

// Problem constants: A=64, T=512, D=256, H=4, HD=64
#define NFEAT 8388608   // 64*512*256

// ---------- staging helpers ----------
// fp16 source via DMA: 128 rows x 64 cols -> packed LDS [128][64], XOR swizzle
__device__ __forceinline__ void stage_dma(
    const _Float16* __restrict__ src, _Float16* __restrict__ lds,
    int wid, int lane)
{
#pragma unroll
    for (int i = 0; i < 4; ++i) {
        int grp = wid * 4 + i;             // 16 groups of 8 rows
        int row = grp * 8 + (lane >> 3);
        int sc  = (lane & 7) ^ (row & 7);  // source chunk for this dest slot
        GLOAD_LDS16(src + (size_t)row * 256 + sc * 8, lds + grp * 512);
    }
}

// fp32 source, cvt in-register: 128 rows x 64 cols -> LDS rows of dst_stride,
// XOR swizzle within the 8-chunk slab
__device__ __forceinline__ void stage_f32_s(
    const float* __restrict__ src, _Float16* __restrict__ lds, int tid,
    int dst_stride)
{
#pragma unroll
    for (int i = 0; i < 4; ++i) {
        int g   = tid + 256 * i;           // 1024 groups of 8 halfs
        int row = g >> 3, chd = g & 7;
        int chs = chd ^ (row & 7);
        const float* s = src + (size_t)row * 256 + chs * 8;
        float4 v0 = *(const float4*)s;
        float4 v1 = *(const float4*)(s + 4);
        half8 h = { (_Float16)v0.x, (_Float16)v0.y, (_Float16)v0.z, (_Float16)v0.w,
                    (_Float16)v1.x, (_Float16)v1.y, (_Float16)v1.z, (_Float16)v1.w };
        *(half8*)(&lds[row * dst_stride + chd * 8]) = h;
    }
}

// ---------- fused QKV GEMM ----------
// 1D grid 512 blocks: xcd = n&7; per XCD: 32 bm x 2 bn (bn pair adjacent ->
// same XCD L2 serves the shared X tile). X tile [128x256] staged ONCE (fp32->
// fp16 inline), then 3 weight GEMMs (z = Q,K,V) run against it.
// LDS 80 KB -> exactly 2 blocks/CU.
__global__ __launch_bounds__(256) void qkv_fused(
    const float* __restrict__ feat,
    const float* __restrict__ Wq, const float* __restrict__ Wk,
    const float* __restrict__ Wv,
    const float* __restrict__ bq, const float* __restrict__ bk,
    const float* __restrict__ bv,
    _Float16* __restrict__ Qb, _Float16* __restrict__ Kb, _Float16* __restrict__ Vb)
{
    __shared__ _Float16 Xs[128 * 256];   // 64 KB, XOR-swizzled per 64-col slab
    __shared__ _Float16 Ws[128 * 64];    // 16 KB

    const int n   = blockIdx.x;
    const int idx = n >> 3;
    const int bm  = (n & 7) * 32 + (idx >> 1);
    const int bn  = idx & 1;

    const int tid  = threadIdx.x;
    const int lane = tid & 63, wid = tid >> 6;
    const int quad = lane >> 4, l16 = lane & 15;
    const int wm = wid & 1, wn = wid >> 1;

    // stage X tile once: 4 slabs of 64 cols
    const float* Xg = feat + (size_t)bm * 128 * 256;
#pragma unroll
    for (int slab = 0; slab < 4; ++slab)
        stage_f32_s(Xg + slab * 64, Xs + slab * 64, tid, 256);
    __syncthreads();

#pragma unroll 1
    for (int z = 0; z < 3; ++z) {
        const float* W    = (z == 0) ? Wq : (z == 1) ? Wk : Wv;
        const float* bias = (z == 0) ? bq : (z == 1) ? bk : bv;
        _Float16*    outp = (z == 0) ? Qb : (z == 1) ? Kb : Vb;
        const float* Wg = W + (size_t)bn * 128 * 256;

        floatx4 acc[4][4] = {};
#pragma unroll 1
        for (int ks = 0; ks < 4; ++ks) {   // k0 = ks*64
            stage_f32_s(Wg + ks * 64, Ws, tid, 64);
            __syncthreads();
#pragma unroll
            for (int kh = 0; kh < 2; ++kh) {
                half8 af[4], bf[4];
#pragma unroll
                for (int mi = 0; mi < 4; ++mi) {
                    int row = wm * 64 + mi * 16 + l16;
                    int cs  = (kh * 4 + quad) ^ (row & 7);
                    af[mi] = *(const half8*)(&Xs[row * 256 + ks * 64 + cs * 8]);
                }
#pragma unroll
                for (int ni = 0; ni < 4; ++ni) {
                    int row = wn * 64 + ni * 16 + l16;
                    int cs  = (kh * 4 + quad) ^ (row & 7);
                    bf[ni] = *(const half8*)(&Ws[row * 64 + cs * 8]);
                }
#pragma unroll
                for (int mi = 0; mi < 4; ++mi)
#pragma unroll
                    for (int ni = 0; ni < 4; ++ni)
                        acc[mi][ni] = MFMA16(af[mi], bf[ni], acc[mi][ni]);
            }
            __syncthreads();
        }

        // epilogue z: C/D layout col = lane&15, row = quad*4 + r
#pragma unroll
        for (int ni = 0; ni < 4; ++ni) {
            int col = bn * 128 + wn * 64 + ni * 16 + l16;
            float bv2 = bias[col];
#pragma unroll
            for (int mi = 0; mi < 4; ++mi)
#pragma unroll
                for (int r = 0; r < 4; ++r) {
                    int row = bm * 128 + wm * 64 + mi * 16 + quad * 4 + r;
                    outp[(size_t)row * 256 + col] = (_Float16)(acc[mi][ni][r] + bv2);
                }
        }
    }
}

// ---------- out GEMM: C[128x128] = attnH[128x256] * Wo[...]^T + bias ----------
__global__ __launch_bounds__(256) void out_gemm(
    const _Float16* __restrict__ attnH, const float* __restrict__ Wo,
    const float* __restrict__ bo, float* __restrict__ out)
{
    __shared__ _Float16 As[128 * 64];
    __shared__ _Float16 Bs[128 * 64];

    const int n   = blockIdx.x;
    const int idx = n >> 3;
    const int bm  = (n & 7) * 32 + (idx >> 1);
    const int bn  = idx & 1;

    const int tid  = threadIdx.x;
    const int lane = tid & 63, wid = tid >> 6;
    const int quad = lane >> 4, l16 = lane & 15;
    const int wm = wid & 1, wn = wid >> 1;

    floatx4 acc[4][4] = {};
    const float* Wg = Wo + (size_t)bn * 128 * 256;

    for (int k0 = 0; k0 < 256; k0 += 64) {
        stage_dma(attnH + (size_t)bm * 128 * 256 + k0, As, wid, lane);
        stage_f32_s(Wg + k0, Bs, tid, 64);
        __syncthreads();
#pragma unroll
        for (int kh = 0; kh < 2; ++kh) {
            half8 af[4], bf[4];
#pragma unroll
            for (int mi = 0; mi < 4; ++mi) {
                int row = wm * 64 + mi * 16 + l16;
                int cs  = (kh * 4 + quad) ^ (row & 7);
                af[mi] = *(const half8*)(&As[row * 64 + cs * 8]);
            }
#pragma unroll
            for (int ni = 0; ni < 4; ++ni) {
                int row = wn * 64 + ni * 16 + l16;
                int cs  = (kh * 4 + quad) ^ (row & 7);
                bf[ni] = *(const half8*)(&Bs[row * 64 + cs * 8]);
            }
#pragma unroll
            for (int mi = 0; mi < 4; ++mi)
#pragma unroll
                for (int ni = 0; ni < 4; ++ni)
                    acc[mi][ni] = MFMA16(af[mi], bf[ni], acc[mi][ni]);
        }
        __syncthreads();
    }

#pragma unroll
    for (int ni = 0; ni < 4; ++ni) {
        int col = bn * 128 + wn * 64 + ni * 16 + l16;
        float bv = bo[col];
#pragma unroll
        for (int mi = 0; mi < 4; ++mi)
#pragma unroll
            for (int r = 0; r < 4; ++r) {
                int row = bm * 128 + wm * 64 + mi * 16 + quad * 4 + r;
                out[(size_t)row * 256 + col] = acc[mi][ni][r] + bv;
            }
    }
}

// ---------- banded sparse attention ----------
// 1D grid 2048: xcd = n&7; per XCD 8 animals x (8 qt x 4 h), h fastest then qt
// (adjacent qtiles share K/V band rows -> same-XCD L2 locality).
__global__ __launch_bounds__(256) void attn_kernel(
    const _Float16* __restrict__ Qb, const _Float16* __restrict__ Kb,
    const _Float16* __restrict__ Vb, const float* __restrict__ positions,
    const int* __restrict__ mdp, const int* __restrict__ twp,
    _Float16* __restrict__ attnb)
{
    const int n   = blockIdx.x;
    const int idx = n >> 3;
    const int a   = (n & 7) * 8 + (idx >> 5);
    const int rem = idx & 31;
    const int qt  = rem >> 2, h = rem & 3;

    const int q0 = qt * 64;
    const int s_base = q0 - 64;
    const int tid = threadIdx.x, lane = tid & 63, wid = tid >> 6;
    const int quad = lane >> 4, l16 = lane & 15;

    // LDS 48 KB -> 3 blocks/CU
    __shared__ _Float16 KPs[192 * 64];   // packed K (XOR), reused as packed P
    __shared__ _Float16 Vt[64 * 192];    // packed V^T (XOR chunk swizzle)

    const size_t abase = (size_t)a * 512;
    const int md = *mdp, tw = *twp;
    const float md2 = (float)(md * md);

    // ---- hoisted per-wave Q fragment + q-position loads ----
    const size_t qrow = abase + q0 + wid * 16 + l16;
    half8 aq0 = *(const half8*)(Qb + qrow * 256 + h * 64 + quad * 8);
    half8 aq1 = *(const half8*)(Qb + qrow * 256 + h * 64 + 32 + quad * 8);
    float qpx[4], qpy[4];
    int trow[4];
#pragma unroll
    for (int r = 0; r < 4; ++r) {
        int m = wid * 16 + quad * 4 + r;
        trow[r] = q0 + m;
        float2 qp = *(const float2*)(positions + (abase + q0 + m) * 2);
        qpx[r] = qp.x;
        qpy[r] = qp.y;
    }

    // ---- stage K band via DMA: packed [192][64], source-side XOR swizzle ----
#pragma unroll
    for (int i = 0; i < 6; ++i) {
        int grp = wid * 6 + i;             // 24 groups of 8 rows
        int si  = grp * 8 + (lane >> 3);
        int sc  = min(max(s_base + si, 0), 511);
        int ch  = (lane & 7) ^ (si & 7);
        GLOAD_LDS16(Kb + (abase + sc) * 256 + h * 64 + ch * 8, KPs + grp * 512);
    }
    // ---- stage V^T packed [64][192], XOR chunk swizzle, paired b32 writes ----
#pragma unroll
    for (int i = 0; i < 3; ++i) {
        int g   = tid + 256 * i;           // 768 pair-groups
        int si2 = (g % 96) * 2;
        int d0  = (g / 96) * 8;
        int sa  = min(max(s_base + si2, 0), 511);
        int sb  = min(max(s_base + si2 + 1, 0), 511);
        half8 v0 = *(const half8*)(Vb + (abase + sa) * 256 + h * 64 + d0);
        half8 v1 = *(const half8*)(Vb + (abase + sb) * 256 + h * 64 + d0);
        int c = si2 >> 3;                  // chunk within 24
#pragma unroll
        for (int j = 0; j < 8; ++j) {
            int d  = d0 + j;
            int cs = (c & ~7) | ((c & 7) ^ (d & 7));
            union { _Float16 hh[2]; uint32_t u; } p;
            p.hh[0] = v0[j]; p.hh[1] = v1[j];
            *(uint32_t*)(&Vt[d * 192 + cs * 8 + (si2 & 7)]) = p.u;
        }
    }
    __syncthreads();

    // ---- S = Q K^T over 12 key tiles ----
    floatx4 S[12];
#pragma unroll
    for (int j = 0; j < 12; ++j) {
        int si = j * 16 + l16;
        half8 bk0 = *(const half8*)(&KPs[si * 64 + ((quad) ^ (si & 7)) * 8]);
        half8 bk1 = *(const half8*)(&KPs[si * 64 + ((4 + quad) ^ (si & 7)) * 8]);
        floatx4 acc = {};
        acc = MFMA16(aq0, bk0, acc);
        acc = MFMA16(aq1, bk1, acc);
        int sr = s_base + si;
        int sc = min(max(sr, 0), 511);
        float2 kp = *(const float2*)(positions + (abase + sc) * 2);
        bool svalid = (sr >= 0) && (sr < 512);
#pragma unroll
        for (int r = 0; r < 4; ++r) {
            float dx = qpx[r] - kp.x, dy = qpy[r] - kp.y;
            float d2 = dx * dx + dy * dy;
            int dt = trow[r] - sr; dt = dt < 0 ? -dt : dt;
            bool ok = svalid && (d2 <= md2) && (dt <= tw);
            S[j][r] = ok ? acc[r] * 0.125f : -1e30f;   // scale = 1/sqrt(64)
        }
    }

    // ---- softmax (exact; quad shuffles) ----
    float minv[4];
#pragma unroll
    for (int r = 0; r < 4; ++r) {
        float m = -1e30f;
#pragma unroll
        for (int j = 0; j < 12; ++j) m = fmaxf(m, S[j][r]);
        m = fmaxf(m, __shfl_xor(m, 1));
        m = fmaxf(m, __shfl_xor(m, 2));
        m = fmaxf(m, __shfl_xor(m, 4));
        m = fmaxf(m, __shfl_xor(m, 8));
        float l = 0.f;
#pragma unroll
        for (int j = 0; j < 12; ++j) {
            float p = __expf(S[j][r] - m);
            S[j][r] = p;
            l += p;
        }
        l += __shfl_xor(l, 1);
        l += __shfl_xor(l, 2);
        l += __shfl_xor(l, 4);
        l += __shfl_xor(l, 8);
        minv[r] = 1.0f / l;
    }

    __syncthreads();   // all waves done reading K before P overwrites it

    // ---- write P into packed-XOR A layout [wave][16][192] over the K region ----
    _Float16* Ps = KPs + wid * (16 * 192);
#pragma unroll
    for (int j = 0; j < 12; ++j)
#pragma unroll
        for (int r = 0; r < 4; ++r) {
            int row = quad * 4 + r;
            int col = j * 16 + l16;
            int ch  = (col >> 3) ^ (row & 7);
            Ps[row * 192 + ch * 8 + (col & 7)] = (_Float16)(S[j][r] * minv[r]);
        }

    // ---- O = P V : M=16, K=192 (6 steps), N=64 (4 tiles) ----
    half8 af[6];
#pragma unroll
    for (int k = 0; k < 6; ++k) {
        int ch = (k * 4 + quad) ^ (l16 & 7);
        af[k] = *(const half8*)(&Ps[l16 * 192 + ch * 8]);
    }
#pragma unroll
    for (int nn = 0; nn < 4; ++nn) {
        floatx4 accO = {};
#pragma unroll
        for (int k = 0; k < 6; ++k) {
            int row = nn * 16 + l16;
            int c   = k * 4 + quad;
            int cs  = (c & ~7) | ((c & 7) ^ (row & 7));
            half8 bv = *(const half8*)(&Vt[row * 192 + cs * 8]);
            accO = MFMA16(af[k], bv, accO);
        }
#pragma unroll
        for (int r = 0; r < 4; ++r) {
            int row = q0 + wid * 16 + quad * 4 + r;
            attnb[(abase + row) * 256 + h * 64 + nn * 16 + l16] = (_Float16)accO[r];
        }
    }
}

// ---------- launch ----------
extern "C" void kernel_launch(void* const* d_in, const int* in_sizes, int n_in,
                              void* d_out, int out_size, void* d_ws, size_t ws_size,
                              hipStream_t stream)
{
    const float* feat = (const float*)d_in[0];
    const float* pos  = (const float*)d_in[1];
    const float* Wq   = (const float*)d_in[2];
    const float* bq   = (const float*)d_in[3];
    const float* Wk   = (const float*)d_in[4];
    const float* bk   = (const float*)d_in[5];
    const float* Wv   = (const float*)d_in[6];
    const float* bv   = (const float*)d_in[7];
    const float* Wo   = (const float*)d_in[8];
    const float* bo   = (const float*)d_in[9];
    const int*   md   = (const int*)d_in[10];
    const int*   tw   = (const int*)d_in[11];
    float*       out  = (float*)d_out;

    _Float16* ws    = (_Float16*)d_ws;
    _Float16* Qb    = ws;
    _Float16* Kb    = Qb + NFEAT;
    _Float16* Vb    = Kb + NFEAT;
    _Float16* attnH = Vb + NFEAT;      // 64 MB of d_ws

    qkv_fused<<<512, 256, 0, stream>>>(feat, Wq, Wk, Wv, bq, bk, bv, Qb, Kb, Vb);

    attn_kernel<<<2048, 256, 0, stream>>>(Qb, Kb, Vb, pos, md, tw, attnH);

    out_gemm<<<512, 256, 0, stream>>>(attnH, Wo, bo, out);
}